// Round 3
// baseline (174.424 us; speedup 1.0000x reference)
//
#include <hip/hip_runtime.h>
#include <math.h>

// ---------------------------------------------------------------------------
// A3C_LSTM_GA forward, batch=1, restructured to avoid ALL cross-WG sync.
//   K1 a3c_pre  (6 blocks x 256): image MLP; gates_h = hx@lstm_wh.T+lbh;
//                                 head-bias init out[0..4] = bias + temb part
//   K2 a3c_scan (1 block x 768):  GRU scan with gru_wh held as f16 in VGPRs
//                                 (one gate-row per thread, v_dot2_f32_f16),
//                                 gi precomputed to LDS f16; then attention +
//                                 fuse + lin in-block (h_enc lives in LDS)
//   K3 a3c_post (4 blocks x 256): LSTM gates -> h_new/c_new -> head partials
//                                 via atomicAdd (out[0..4] pre-initialized)
// No spin loops, no flags; inter-block dataflow only via kernel boundaries.
// ---------------------------------------------------------------------------

typedef __fp16 h2 __attribute__((ext_vector_type(2)));

// ws layout (float offsets)
#define WS_IMG    0      // 128
#define WS_GATESH 128    // 1024
#define WS_FUSED  1152   // 256

__device__ __forceinline__ float dot4(const float4 a, const float4 b){
  return a.x*b.x + a.y*b.y + a.z*b.z + a.w*b.w;
}
__device__ __forceinline__ float sigm(float x){ return 1.f/(1.f+expf(-x)); }

// ------------------------------------------------------------------- K1
__global__ __launch_bounds__(256) void a3c_pre(
    const float* __restrict__ x,
    const float* __restrict__ i1w, const float* __restrict__ i1b,
    const float* __restrict__ i2w, const float* __restrict__ i2b,
    const float* __restrict__ i3w, const float* __restrict__ i3b,
    const float* __restrict__ hx,  const float* __restrict__ lwh,
    const float* __restrict__ lbh,
    const int*   __restrict__ tx,  const float* __restrict__ temb,
    const float* __restrict__ cw,  const float* __restrict__ cb,
    const float* __restrict__ acw, const float* __restrict__ acb,
    float* __restrict__ ws, float* __restrict__ out)
{
  const int b = blockIdx.x;
  const int t = threadIdx.x;

  if (b == 0) {
    // image MLP 400 -> 128 -> 128 -> 128
    __shared__ __align__(16) float x_lds[400];
    __shared__ __align__(16) float h1[128];
    __shared__ __align__(16) float h2s[128];
    x_lds[t] = x[t];
    if (t < 144) x_lds[256+t] = x[256+t];
    __syncthreads();
    {
      const int o = t>>1, half = t&1;
      const float4* wr = (const float4*)(i1w + o*400 + half*200);
      const float4* xr = (const float4*)(x_lds + half*200);
      float acc = 0.f;
      #pragma unroll 5
      for (int k=0;k<50;++k) acc += dot4(wr[k], xr[k]);
      acc += __shfl_down(acc, 1, 2);
      if (half == 0) h1[o] = fmaxf(acc + i1b[o], 0.f);
    }
    __syncthreads();
    if (t < 128){
      const float4* wr = (const float4*)(i2w + t*128);
      const float4* h4 = (const float4*)h1;
      float acc = i2b[t];
      #pragma unroll 8
      for (int k=0;k<32;++k) acc += dot4(wr[k], h4[k]);
      h2s[t] = fmaxf(acc, 0.f);
    }
    __syncthreads();
    if (t < 128){
      const float4* wr = (const float4*)(i3w + t*128);
      const float4* h4 = (const float4*)h2s;
      float acc = i3b[t];
      #pragma unroll 8
      for (int k=0;k<32;++k) acc += dot4(wr[k], h4[k]);
      ws[WS_IMG + t] = fmaxf(acc, 0.f);
    }

  } else if (b == 5) {
    // out[0..4] = bias + time-embedding partial of the heads
    if (t < 64){
      float tv = 0.f;
      if (t < 32) tv = temb[tx[0]*32 + t];
      #pragma unroll
      for (int o=0;o<5;++o){
        const float* wrow = (o==0) ? cw : (acw + (o-1)*288);
        float pr = (t < 32) ? tv*wrow[256+t] : 0.f;
        #pragma unroll
        for (int off=16; off; off>>=1) pr += __shfl_down(pr, off, 32);
        if (t == 0) out[o] = pr + ((o==0) ? cb[0] : acb[o-1]);
      }
    }

  } else {
    // blocks 1..4: gates_h = hx @ lstm_wh.T + lstm_bh
    __shared__ __align__(16) float hx_lds[256];
    hx_lds[t] = hx[t];
    __syncthreads();
    const int R = (b-1)*256 + t;
    const float4* wr = (const float4*)(lwh + R*256);
    const float4* h4 = (const float4*)hx_lds;
    float acc = lbh[R];
    #pragma unroll 8
    for (int k=0;k<64;++k) acc += dot4(wr[k], h4[k]);
    ws[WS_GATESH + R] = acc;
  }
}

// ------------------------------------------------------------------- K2
__global__ __launch_bounds__(768) void a3c_scan(
    const int*   __restrict__ inst, const float* __restrict__ emb,
    const float* __restrict__ gwi,  const float* __restrict__ gwh,
    const float* __restrict__ gbi,  const float* __restrict__ gbh,
    const float* __restrict__ aw,   const float* __restrict__ ab,
    const float* __restrict__ lw,   const float* __restrict__ lb,
    float* __restrict__ ws)
{
  const int t = threadIdx.x;           // gate-row owned by this thread
  __shared__ __fp16 gi16[64*768];                   // 96 KB
  __shared__ __align__(16) h2 e16[1024];            // 4 KB  (emb_seq f16)
  __shared__ __align__(16) float h32[256];
  __shared__ __align__(16) h2 h16[128];
  __shared__ float pre[768];
  __shared__ float hn[256];
  __shared__ __align__(16) float f0[128];

  // emb_seq -> f16 LDS
  for (int i=t; i<2048; i+=768)
    ((__fp16*)e16)[i] = (__fp16)emb[inst[i>>5]*32 + (i&31)];
  const float bh_t = gbh[t];
  const float bi_t = gbi[t];
  __syncthreads();

  // gi16[s][t] = gru_wi[row t] . e_s + gbi[t]
  {
    h2 wi[16];
    const float4* wp = (const float4*)(gwi + t*32);
    #pragma unroll
    for (int k=0;k<8;++k){
      float4 w = wp[k];
      wi[2*k]   = __builtin_amdgcn_cvt_pkrtz(w.x, w.y);
      wi[2*k+1] = __builtin_amdgcn_cvt_pkrtz(w.z, w.w);
    }
    for (int s=0;s<64;++s){
      const h2* ep = e16 + s*16;
      float a0 = bi_t, a1 = 0.f;
      #pragma unroll
      for (int k=0;k<8;++k)  a0 = __builtin_amdgcn_fdot2(wi[k], ep[k], a0, false);
      #pragma unroll
      for (int k=8;k<16;++k) a1 = __builtin_amdgcn_fdot2(wi[k], ep[k], a1, false);
      gi16[s*768 + t] = (__fp16)(a0 + a1);
    }
  }

  // gru_wh row t -> 128 half2 VGPRs (full row, 256 cols)
  h2 wh[128];
  {
    const float4* wp = (const float4*)(gwh + t*256);
    #pragma unroll
    for (int k=0;k<64;++k){
      float4 w = wp[k];
      wh[2*k]   = __builtin_amdgcn_cvt_pkrtz(w.x, w.y);
      wh[2*k+1] = __builtin_amdgcn_cvt_pkrtz(w.z, w.w);
    }
  }
  if (t < 256){ h32[t] = 0.f; ((__fp16*)h16)[t] = (__fp16)0.f; }
  __syncthreads();

  // ---------------- 64-step scan, zero cross-WG traffic ----------------
  for (int s=0;s<64;++s){
    const float gi_s = (float)gi16[s*768 + t];
    float a0 = bh_t, a1 = 0.f, a2 = 0.f, a3 = 0.f;
    #pragma unroll
    for (int k=0;  k<32; ++k) a0 = __builtin_amdgcn_fdot2(wh[k], h16[k], a0, false);
    #pragma unroll
    for (int k=32; k<64; ++k) a1 = __builtin_amdgcn_fdot2(wh[k], h16[k], a1, false);
    #pragma unroll
    for (int k=64; k<96; ++k) a2 = __builtin_amdgcn_fdot2(wh[k], h16[k], a2, false);
    #pragma unroll
    for (int k=96; k<128;++k) a3 = __builtin_amdgcn_fdot2(wh[k], h16[k], a3, false);
    const float acc = (a0+a1)+(a2+a3);       // wh_row . h + bh
    if (t < 512) pre[t] = gi_s + acc;        // r,z pre-activations
    else       { pre[t] = gi_s; hn[t-512] = acc; }   // i_n and hn separate
    __syncthreads();
    if (t < 256){
      const float r  = sigm(pre[t]);
      const float z  = sigm(pre[256+t]);
      const float n  = tanhf(pre[512+t] + r*hn[t]);
      const float hv = (1.f - z)*n + z*h32[t];
      h32[t] = hv;
      ((__fp16*)h16)[t] = (__fp16)hv;
    }
    __syncthreads();
  }

  // ---------------- attention -> fuse -> lin (h_enc == h32) ------------
  if (t < 128){
    const float4* wr = (const float4*)(aw + t*256);
    const float4* h4 = (const float4*)h32;
    float acc = ab[t];
    #pragma unroll 8
    for (int k=0;k<64;++k) acc += dot4(wr[k], h4[k]);
    f0[t] = ws[WS_IMG + t] * sigm(acc);
  }
  __syncthreads();
  if (t < 256){
    const float4* wr = (const float4*)(lw + t*128);
    const float4* h4 = (const float4*)f0;
    float acc = lb[t];
    #pragma unroll 8
    for (int k=0;k<32;++k) acc += dot4(wr[k], h4[k]);
    ws[WS_FUSED + t] = fmaxf(acc, 0.f);
  }
}

// ------------------------------------------------------------------- K3
__global__ __launch_bounds__(256) void a3c_post(
    const float* __restrict__ lwi, const float* __restrict__ lbi,
    const float* __restrict__ cx,
    const float* __restrict__ cw,  const float* __restrict__ acw,
    float* __restrict__ ws, float* __restrict__ out)
{
  const int p = blockIdx.x;            // 0..3, owns 64 LSTM units
  const int t = threadIdx.x;
  __shared__ __align__(16) float fused_lds[256];
  __shared__ float gv[256];
  __shared__ float hh[64];
  fused_lds[t] = ws[WS_FUSED + t];
  __syncthreads();
  const int g = t>>6, ul = t&63;
  const int R = (g<<8) + p*64 + ul;
  const float4* wr = (const float4*)(lwi + R*256);
  const float4* f4 = (const float4*)fused_lds;
  float acc = ws[WS_GATESH + R] + lbi[R];
  #pragma unroll 8
  for (int k=0;k<64;++k) acc += dot4(wr[k], f4[k]);
  gv[t] = acc;
  __syncthreads();
  if (t < 64){
    const int u2 = p*64 + t;
    const float iv = gv[t], fv = gv[64+t], gg = gv[128+t], ov = gv[192+t];
    const float c = sigm(fv)*cx[u2] + sigm(iv)*tanhf(gg);
    const float h = sigm(ov)*tanhf(c);
    out[5   + u2] = h;
    out[261 + u2] = c;
    hh[t] = h;
  }
  __syncthreads();
  if (t < 64){
    #pragma unroll
    for (int o=0;o<5;++o){
      const float* wrow = (o==0) ? cw : (acw + (o-1)*288);
      float pr = hh[t]*wrow[p*64 + t];
      #pragma unroll
      for (int off=32; off; off>>=1) pr += __shfl_down(pr, off, 64);
      if (t == 0) atomicAdd(out + o, pr);
    }
  }
}

extern "C" void kernel_launch(void* const* d_in, const int* in_sizes, int n_in,
                              void* d_out, int out_size, void* d_ws, size_t ws_size,
                              hipStream_t stream) {
  (void)in_sizes; (void)n_in; (void)out_size; (void)ws_size;
  const float* x    = (const float*)d_in[0];
  const int*   inst = (const int*)  d_in[1];
  const int*   tx   = (const int*)  d_in[2];
  const float* hx   = (const float*)d_in[3];
  const float* cx   = (const float*)d_in[4];
  const float* i1w  = (const float*)d_in[5];
  const float* i1b  = (const float*)d_in[6];
  const float* i2w  = (const float*)d_in[7];
  const float* i2b  = (const float*)d_in[8];
  const float* i3w  = (const float*)d_in[9];
  const float* i3b  = (const float*)d_in[10];
  const float* emb  = (const float*)d_in[11];
  const float* gwi  = (const float*)d_in[12];
  const float* gwh  = (const float*)d_in[13];
  const float* gbi  = (const float*)d_in[14];
  const float* gbh  = (const float*)d_in[15];
  const float* aw   = (const float*)d_in[16];
  const float* ab   = (const float*)d_in[17];
  const float* temb = (const float*)d_in[18];
  const float* lw   = (const float*)d_in[19];
  const float* lb   = (const float*)d_in[20];
  const float* lwi  = (const float*)d_in[21];
  const float* lwh  = (const float*)d_in[22];
  const float* lbi  = (const float*)d_in[23];
  const float* lbh  = (const float*)d_in[24];
  const float* cw   = (const float*)d_in[25];
  const float* cb   = (const float*)d_in[26];
  const float* acw  = (const float*)d_in[27];
  const float* acb  = (const float*)d_in[28];
  float* ws  = (float*)d_ws;
  float* out = (float*)d_out;

  a3c_pre <<<6, 256, 0, stream>>>(x, i1w, i1b, i2w, i2b, i3w, i3b,
                                  hx, lwh, lbh, tx, temb, cw, cb, acw, acb,
                                  ws, out);
  a3c_scan<<<1, 768, 0, stream>>>(inst, emb, gwi, gwh, gbi, gbh,
                                  aw, ab, lw, lb, ws);
  a3c_post<<<4, 256, 0, stream>>>(lwi, lbi, cx, cw, acw, ws, out);
}

// Round 4
// 158.986 us; speedup vs baseline: 1.0971x; 1.0971x over previous
//
#include <hip/hip_runtime.h>
#include <math.h>

// ---------------------------------------------------------------------------
// A3C_LSTM_GA forward, batch=1.  No cross-WG sync anywhere.
//   K1 a3c_pre  (6 blocks x 256): image MLP; gates_h = hx@lstm_wh.T+lbh;
//                                 head-bias init out[0..4]
//   K2 a3c_scan (1 block x 768, launch_bounds(768,3) -> ~168 VGPR):
//       GRU scan. Thread t=2p+j owns gate-rows {2p,2p+1} col-half j as f16
//       in 128 VGPRs; per step reads 256B of h (2-way LDS broadcast, free),
//       one shfl_xor(1) combines halves so thread t holds full dot of row t.
//       gi precomputed to LDS f16. Attention+fuse+lin fused at the end.
//   K3 a3c_post (4 blocks x 256): LSTM gates -> h/c -> head atomicAdd partials
// ---------------------------------------------------------------------------

typedef __fp16 h2 __attribute__((ext_vector_type(2)));

// ws layout (float offsets)
#define WS_IMG    0      // 128
#define WS_GATESH 128    // 1024
#define WS_FUSED  1152   // 256

__device__ __forceinline__ float dot4(const float4 a, const float4 b){
  return a.x*b.x + a.y*b.y + a.z*b.z + a.w*b.w;
}
__device__ __forceinline__ float sigm(float x){ return 1.f/(1.f+expf(-x)); }

// ------------------------------------------------------------------- K1
__global__ __launch_bounds__(256) void a3c_pre(
    const float* __restrict__ x,
    const float* __restrict__ i1w, const float* __restrict__ i1b,
    const float* __restrict__ i2w, const float* __restrict__ i2b,
    const float* __restrict__ i3w, const float* __restrict__ i3b,
    const float* __restrict__ hx,  const float* __restrict__ lwh,
    const float* __restrict__ lbh,
    const int*   __restrict__ tx,  const float* __restrict__ temb,
    const float* __restrict__ cw,  const float* __restrict__ cb,
    const float* __restrict__ acw, const float* __restrict__ acb,
    float* __restrict__ ws, float* __restrict__ out)
{
  const int b = blockIdx.x;
  const int t = threadIdx.x;

  if (b == 0) {
    // image MLP 400 -> 128 -> 128 -> 128
    __shared__ __align__(16) float x_lds[400];
    __shared__ __align__(16) float h1[128];
    __shared__ __align__(16) float h2s[128];
    x_lds[t] = x[t];
    if (t < 144) x_lds[256+t] = x[256+t];
    __syncthreads();
    {
      const int o = t>>1, half = t&1;
      const float4* wr = (const float4*)(i1w + o*400 + half*200);
      const float4* xr = (const float4*)(x_lds + half*200);
      float acc = 0.f;
      #pragma unroll 5
      for (int k=0;k<50;++k) acc += dot4(wr[k], xr[k]);
      acc += __shfl_down(acc, 1, 2);
      if (half == 0) h1[o] = fmaxf(acc + i1b[o], 0.f);
    }
    __syncthreads();
    if (t < 128){
      const float4* wr = (const float4*)(i2w + t*128);
      const float4* h4 = (const float4*)h1;
      float acc = i2b[t];
      #pragma unroll 8
      for (int k=0;k<32;++k) acc += dot4(wr[k], h4[k]);
      h2s[t] = fmaxf(acc, 0.f);
    }
    __syncthreads();
    if (t < 128){
      const float4* wr = (const float4*)(i3w + t*128);
      const float4* h4 = (const float4*)h2s;
      float acc = i3b[t];
      #pragma unroll 8
      for (int k=0;k<32;++k) acc += dot4(wr[k], h4[k]);
      ws[WS_IMG + t] = fmaxf(acc, 0.f);
    }

  } else if (b == 5) {
    // out[0..4] = bias + time-embedding partial of the heads
    if (t < 64){
      float tv = 0.f;
      if (t < 32) tv = temb[tx[0]*32 + t];
      #pragma unroll
      for (int o=0;o<5;++o){
        const float* wrow = (o==0) ? cw : (acw + (o-1)*288);
        float pr = (t < 32) ? tv*wrow[256+t] : 0.f;
        #pragma unroll
        for (int off=16; off; off>>=1) pr += __shfl_down(pr, off, 32);
        if (t == 0) out[o] = pr + ((o==0) ? cb[0] : acb[o-1]);
      }
    }

  } else {
    // blocks 1..4: gates_h = hx @ lstm_wh.T + lstm_bh
    __shared__ __align__(16) float hx_lds[256];
    hx_lds[t] = hx[t];
    __syncthreads();
    const int R = (b-1)*256 + t;
    const float4* wr = (const float4*)(lwh + R*256);
    const float4* h4 = (const float4*)hx_lds;
    float acc = lbh[R];
    #pragma unroll 8
    for (int k=0;k<64;++k) acc += dot4(wr[k], h4[k]);
    ws[WS_GATESH + R] = acc;
  }
}

// ------------------------------------------------------------------- K2
__global__ __launch_bounds__(768, 3) void a3c_scan(
    const int*   __restrict__ inst, const float* __restrict__ emb,
    const float* __restrict__ gwi,  const float* __restrict__ gwh,
    const float* __restrict__ gbi,  const float* __restrict__ gbh,
    const float* __restrict__ aw,   const float* __restrict__ ab,
    const float* __restrict__ lw,   const float* __restrict__ lb,
    float* __restrict__ ws)
{
  const int t = threadIdx.x;           // final owner of gate-row t
  const int p = t >> 1;                // row pair: rows {2p, 2p+1}
  const int j = t & 1;                 // column half [128j, 128j+128)
  __shared__ __fp16 gi16[64*768];                   // 96 KB
  __shared__ __align__(16) h2 e16[1024];            // 4 KB  (emb_seq f16)
  __shared__ __align__(16) float h32[256];
  __shared__ __align__(16) h2 h16[128];
  __shared__ float pre[768];
  __shared__ float hn[256];
  __shared__ __align__(16) float f0[128];

  // emb_seq -> f16 LDS
  for (int i=t; i<2048; i+=768)
    ((__fp16*)e16)[i] = (__fp16)emb[inst[i>>5]*32 + (i&31)];
  const float bh_t = gbh[t];
  const float bi_t = gbi[t];
  __syncthreads();

  // gi16[s][t] = gru_wi[row t] . e_s + gbi[t]
  {
    h2 wi[16];
    const float4* wp = (const float4*)(gwi + t*32);
    #pragma unroll
    for (int k=0;k<8;++k){
      float4 w = wp[k];
      wi[2*k]   = __builtin_amdgcn_cvt_pkrtz(w.x, w.y);
      wi[2*k+1] = __builtin_amdgcn_cvt_pkrtz(w.z, w.w);
    }
    for (int s=0;s<64;++s){
      const h2* ep = e16 + s*16;
      float a0 = bi_t, a1 = 0.f;
      #pragma unroll
      for (int k=0;k<8;++k)  a0 = __builtin_amdgcn_fdot2(wi[k], ep[k], a0, false);
      #pragma unroll
      for (int k=8;k<16;++k) a1 = __builtin_amdgcn_fdot2(wi[k], ep[k], a1, false);
      gi16[s*768 + t] = (__fp16)(a0 + a1);
    }
  }

  // weights: rows {2p, 2p+1}, col-half j -> 2 x 64 h2 = 128 VGPRs
  h2 w0[64], w1[64];
  {
    const float4* wp0 = (const float4*)(gwh + (2*p  )*256 + 128*j);
    const float4* wp1 = (const float4*)(gwh + (2*p+1)*256 + 128*j);
    #pragma unroll
    for (int c=0;c<4;++c){           // chunks of 8 float4 per row half
      #pragma unroll
      for (int k=0;k<8;++k){
        float4 w = wp0[c*8+k];
        w0[c*16+2*k]   = __builtin_amdgcn_cvt_pkrtz(w.x, w.y);
        w0[c*16+2*k+1] = __builtin_amdgcn_cvt_pkrtz(w.z, w.w);
      }
      #pragma unroll
      for (int k=0;k<8;++k){
        float4 w = wp1[c*8+k];
        w1[c*16+2*k]   = __builtin_amdgcn_cvt_pkrtz(w.x, w.y);
        w1[c*16+2*k+1] = __builtin_amdgcn_cvt_pkrtz(w.z, w.w);
      }
    }
  }
  if (t < 256){ h32[t] = 0.f; ((__fp16*)h16)[t] = (__fp16)0.f; }
  __syncthreads();

  // ---------------- 64-step scan ----------------
  const h2* hp = h16 + 64*j;           // this thread's 64-h2 column half
  for (int s=0;s<64;++s){
    const float gi_s = (float)gi16[s*768 + t];
    float a0 = 0.f, a1 = 0.f;          // partials for rows 2p, 2p+1
    #pragma unroll
    for (int k=0;k<64;++k){
      const h2 hv = hp[k];
      a0 = __builtin_amdgcn_fdot2(w0[k], hv, a0, false);
      a1 = __builtin_amdgcn_fdot2(w1[k], hv, a1, false);
    }
    // thread j keeps partial of row 2p+j, sends the other
    const float keep = j ? a1 : a0;
    const float send = j ? a0 : a1;
    const float acc  = keep + __shfl_xor(send, 1) + bh_t;   // full dot row t
    if (t < 512) pre[t] = gi_s + acc;        // r,z pre-activations
    else       { pre[t] = gi_s; hn[t-512] = acc; }   // i_n and hn separate
    __syncthreads();
    if (t < 256){
      const float r  = sigm(pre[t]);
      const float z  = sigm(pre[256+t]);
      const float n  = tanhf(pre[512+t] + r*hn[t]);
      const float hv = (1.f - z)*n + z*h32[t];
      h32[t] = hv;
      ((__fp16*)h16)[t] = (__fp16)hv;
    }
    __syncthreads();
  }

  // ---------------- attention -> fuse -> lin (h_enc == h32) ------------
  if (t < 128){
    const float4* wr = (const float4*)(aw + t*256);
    const float4* h4 = (const float4*)h32;
    float acc = ab[t];
    #pragma unroll 8
    for (int k=0;k<64;++k) acc += dot4(wr[k], h4[k]);
    f0[t] = ws[WS_IMG + t] * sigm(acc);
  }
  __syncthreads();
  if (t < 256){
    const float4* wr = (const float4*)(lw + t*128);
    const float4* h4 = (const float4*)f0;
    float acc = lb[t];
    #pragma unroll 8
    for (int k=0;k<32;++k) acc += dot4(wr[k], h4[k]);
    ws[WS_FUSED + t] = fmaxf(acc, 0.f);
  }
}

// ------------------------------------------------------------------- K3
__global__ __launch_bounds__(256) void a3c_post(
    const float* __restrict__ lwi, const float* __restrict__ lbi,
    const float* __restrict__ cx,
    const float* __restrict__ cw,  const float* __restrict__ acw,
    float* __restrict__ ws, float* __restrict__ out)
{
  const int p = blockIdx.x;            // 0..3, owns 64 LSTM units
  const int t = threadIdx.x;
  __shared__ __align__(16) float fused_lds[256];
  __shared__ float gv[256];
  __shared__ float hh[64];
  fused_lds[t] = ws[WS_FUSED + t];
  __syncthreads();
  const int g = t>>6, ul = t&63;
  const int R = (g<<8) + p*64 + ul;
  const float4* wr = (const float4*)(lwi + R*256);
  const float4* f4 = (const float4*)fused_lds;
  float acc = ws[WS_GATESH + R] + lbi[R];
  #pragma unroll 8
  for (int k=0;k<64;++k) acc += dot4(wr[k], f4[k]);
  gv[t] = acc;
  __syncthreads();
  if (t < 64){
    const int u2 = p*64 + t;
    const float iv = gv[t], fv = gv[64+t], gg = gv[128+t], ov = gv[192+t];
    const float c = sigm(fv)*cx[u2] + sigm(iv)*tanhf(gg);
    const float h = sigm(ov)*tanhf(c);
    out[5   + u2] = h;
    out[261 + u2] = c;
    hh[t] = h;
  }
  __syncthreads();
  if (t < 64){
    #pragma unroll
    for (int o=0;o<5;++o){
      const float* wrow = (o==0) ? cw : (acw + (o-1)*288);
      float pr = hh[t]*wrow[p*64 + t];
      #pragma unroll
      for (int off=32; off; off>>=1) pr += __shfl_down(pr, off, 64);
      if (t == 0) atomicAdd(out + o, pr);
    }
  }
}

extern "C" void kernel_launch(void* const* d_in, const int* in_sizes, int n_in,
                              void* d_out, int out_size, void* d_ws, size_t ws_size,
                              hipStream_t stream) {
  (void)in_sizes; (void)n_in; (void)out_size; (void)ws_size;
  const float* x    = (const float*)d_in[0];
  const int*   inst = (const int*)  d_in[1];
  const int*   tx   = (const int*)  d_in[2];
  const float* hx   = (const float*)d_in[3];
  const float* cx   = (const float*)d_in[4];
  const float* i1w  = (const float*)d_in[5];
  const float* i1b  = (const float*)d_in[6];
  const float* i2w  = (const float*)d_in[7];
  const float* i2b  = (const float*)d_in[8];
  const float* i3w  = (const float*)d_in[9];
  const float* i3b  = (const float*)d_in[10];
  const float* emb  = (const float*)d_in[11];
  const float* gwi  = (const float*)d_in[12];
  const float* gwh  = (const float*)d_in[13];
  const float* gbi  = (const float*)d_in[14];
  const float* gbh  = (const float*)d_in[15];
  const float* aw   = (const float*)d_in[16];
  const float* ab   = (const float*)d_in[17];
  const float* temb = (const float*)d_in[18];
  const float* lw   = (const float*)d_in[19];
  const float* lb   = (const float*)d_in[20];
  const float* lwi  = (const float*)d_in[21];
  const float* lwh  = (const float*)d_in[22];
  const float* lbi  = (const float*)d_in[23];
  const float* lbh  = (const float*)d_in[24];
  const float* cw   = (const float*)d_in[25];
  const float* cb   = (const float*)d_in[26];
  const float* acw  = (const float*)d_in[27];
  const float* acb  = (const float*)d_in[28];
  float* ws  = (float*)d_ws;
  float* out = (float*)d_out;

  a3c_pre <<<6, 256, 0, stream>>>(x, i1w, i1b, i2w, i2b, i3w, i3b,
                                  hx, lwh, lbh, tx, temb, cw, cb, acw, acb,
                                  ws, out);
  a3c_scan<<<1, 768, 0, stream>>>(inst, emb, gwi, gwh, gbi, gbh,
                                  aw, ab, lw, lb, ws);
  a3c_post<<<4, 256, 0, stream>>>(lwi, lbi, cx, cw, acw, ws, out);
}

// Round 5
// 158.982 us; speedup vs baseline: 1.0971x; 1.0000x over previous
//
#include <hip/hip_runtime.h>
#include <math.h>

// ---------------------------------------------------------------------------
// A3C_LSTM_GA forward, batch=1.  No cross-WG sync anywhere.
//   K1 a3c_pre  (6 blocks x 256): image MLP; gates_h = hx@lstm_wh.T+lbh;
//                                 head-bias init out[0..4]
//   K2 a3c_scan (1 block x 768, amdgpu_waves_per_eu(3,3) -> ~170 VGPR budget):
//       GRU scan. Thread t=2p+j owns gate-rows {2p,2p+1} col-half j as f16
//       in 128 VGPRs (macro-unrolled constant indices only); per step reads
//       its 256B h-half as 16 ds_read_b128 broadcasts; shfl_xor(1) combines
//       halves. gi precomputed to LDS f16. Attention+fuse+lin fused at end.
//   K3 a3c_post (4 blocks x 256): LSTM gates -> h/c -> head atomicAdd partials
// ---------------------------------------------------------------------------

typedef __fp16 h2 __attribute__((ext_vector_type(2)));
typedef __fp16 h8 __attribute__((ext_vector_type(8)));

// ws layout (float offsets)
#define WS_IMG    0      // 128
#define WS_GATESH 128    // 1024
#define WS_FUSED  1152   // 256

__device__ __forceinline__ float dot4(const float4 a, const float4 b){
  return a.x*b.x + a.y*b.y + a.z*b.z + a.w*b.w;
}
__device__ __forceinline__ float sigm(float x){ return 1.f/(1.f+expf(-x)); }

#define P0(v) __builtin_shufflevector(v,v,0,1)
#define P1(v) __builtin_shufflevector(v,v,2,3)
#define P2(v) __builtin_shufflevector(v,v,4,5)
#define P3(v) __builtin_shufflevector(v,v,6,7)

// ------------------------------------------------------------------- K1
__global__ __launch_bounds__(256) void a3c_pre(
    const float* __restrict__ x,
    const float* __restrict__ i1w, const float* __restrict__ i1b,
    const float* __restrict__ i2w, const float* __restrict__ i2b,
    const float* __restrict__ i3w, const float* __restrict__ i3b,
    const float* __restrict__ hx,  const float* __restrict__ lwh,
    const float* __restrict__ lbh,
    const int*   __restrict__ tx,  const float* __restrict__ temb,
    const float* __restrict__ cw,  const float* __restrict__ cb,
    const float* __restrict__ acw, const float* __restrict__ acb,
    float* __restrict__ ws, float* __restrict__ out)
{
  const int b = blockIdx.x;
  const int t = threadIdx.x;

  if (b == 0) {
    // image MLP 400 -> 128 -> 128 -> 128
    __shared__ __align__(16) float x_lds[400];
    __shared__ __align__(16) float h1[128];
    __shared__ __align__(16) float h2s[128];
    x_lds[t] = x[t];
    if (t < 144) x_lds[256+t] = x[256+t];
    __syncthreads();
    {
      const int o = t>>1, half = t&1;
      const float4* wr = (const float4*)(i1w + o*400 + half*200);
      const float4* xr = (const float4*)(x_lds + half*200);
      float acc = 0.f;
      #pragma unroll 5
      for (int k=0;k<50;++k) acc += dot4(wr[k], xr[k]);
      acc += __shfl_down(acc, 1, 2);
      if (half == 0) h1[o] = fmaxf(acc + i1b[o], 0.f);
    }
    __syncthreads();
    if (t < 128){
      const float4* wr = (const float4*)(i2w + t*128);
      const float4* h4 = (const float4*)h1;
      float acc = i2b[t];
      #pragma unroll 8
      for (int k=0;k<32;++k) acc += dot4(wr[k], h4[k]);
      h2s[t] = fmaxf(acc, 0.f);
    }
    __syncthreads();
    if (t < 128){
      const float4* wr = (const float4*)(i3w + t*128);
      const float4* h4 = (const float4*)h2s;
      float acc = i3b[t];
      #pragma unroll 8
      for (int k=0;k<32;++k) acc += dot4(wr[k], h4[k]);
      ws[WS_IMG + t] = fmaxf(acc, 0.f);
    }

  } else if (b == 5) {
    // out[0..4] = bias + time-embedding partial of the heads
    if (t < 64){
      float tv = 0.f;
      if (t < 32) tv = temb[tx[0]*32 + t];
      #pragma unroll
      for (int o=0;o<5;++o){
        const float* wrow = (o==0) ? cw : (acw + (o-1)*288);
        float pr = (t < 32) ? tv*wrow[256+t] : 0.f;
        #pragma unroll
        for (int off=16; off; off>>=1) pr += __shfl_down(pr, off, 32);
        if (t == 0) out[o] = pr + ((o==0) ? cb[0] : acb[o-1]);
      }
    }

  } else {
    // blocks 1..4: gates_h = hx @ lstm_wh.T + lstm_bh
    __shared__ __align__(16) float hx_lds[256];
    hx_lds[t] = hx[t];
    __syncthreads();
    const int R = (b-1)*256 + t;
    const float4* wr = (const float4*)(lwh + R*256);
    const float4* h4 = (const float4*)hx_lds;
    float acc = lbh[R];
    #pragma unroll 8
    for (int k=0;k<64;++k) acc += dot4(wr[k], h4[k]);
    ws[WS_GATESH + R] = acc;
  }
}

// ------------------------------------------------------------------- K2
__global__ __launch_bounds__(768) __attribute__((amdgpu_waves_per_eu(3, 3)))
void a3c_scan(
    const int*   __restrict__ inst, const float* __restrict__ emb,
    const float* __restrict__ gwi,  const float* __restrict__ gwh,
    const float* __restrict__ gbi,  const float* __restrict__ gbh,
    const float* __restrict__ aw,   const float* __restrict__ ab,
    const float* __restrict__ lw,   const float* __restrict__ lb,
    float* __restrict__ ws)
{
  const int t = threadIdx.x;           // final owner of gate-row t
  const int p = t >> 1;                // row pair: rows {2p, 2p+1}
  const int j = t & 1;                 // column half [128j, 128j+128)
  __shared__ __fp16 gi16[64*768];                   // 96 KB
  __shared__ __align__(16) __fp16 e16[2048];        // 4 KB  (emb_seq f16)
  __shared__ __align__(16) float h32[256];
  __shared__ __align__(16) __fp16 h16[256];
  __shared__ float pre[768];
  __shared__ float hn[256];
  __shared__ __align__(16) float f0[128];

  // emb_seq -> f16 LDS
  for (int i=t; i<2048; i+=768)
    e16[i] = (__fp16)emb[inst[i>>5]*32 + (i&31)];
  const float bh_t = gbh[t];
  const float bi_t = gbi[t];
  __syncthreads();

  // gi16[s][t] = gru_wi[row t] . e_s + gbi[t]
  {
    h2 wi[16];
    const float4* wp = (const float4*)(gwi + t*32);
    #pragma unroll
    for (int k=0;k<8;++k){
      float4 w = wp[k];
      wi[2*k]   = __builtin_amdgcn_cvt_pkrtz(w.x, w.y);
      wi[2*k+1] = __builtin_amdgcn_cvt_pkrtz(w.z, w.w);
    }
    for (int s=0;s<64;++s){
      const h8* ech = (const h8*)(e16 + s*32);
      float g0 = bi_t;
      #define GIC(c) { const h8 ev = ech[c]; \
        g0 = __builtin_amdgcn_fdot2(wi[4*(c)  ], P0(ev), g0, false); \
        g0 = __builtin_amdgcn_fdot2(wi[4*(c)+1], P1(ev), g0, false); \
        g0 = __builtin_amdgcn_fdot2(wi[4*(c)+2], P2(ev), g0, false); \
        g0 = __builtin_amdgcn_fdot2(wi[4*(c)+3], P3(ev), g0, false); }
      GIC(0) GIC(1) GIC(2) GIC(3)
      #undef GIC
      gi16[s*768 + t] = (__fp16)g0;
    }
  }

  // weights: rows {2p, 2p+1}, col-half j -> 2 x 64 h2 = 128 VGPRs
  h2 w0[64], w1[64];
  {
    const float4* wp0 = (const float4*)(gwh + (2*p  )*256 + 128*j);
    const float4* wp1 = (const float4*)(gwh + (2*p+1)*256 + 128*j);
    #pragma unroll
    for (int c=0;c<4;++c){           // chunks of 8 float4 per row half
      #pragma unroll
      for (int k=0;k<8;++k){
        float4 w = wp0[c*8+k];
        w0[c*16+2*k]   = __builtin_amdgcn_cvt_pkrtz(w.x, w.y);
        w0[c*16+2*k+1] = __builtin_amdgcn_cvt_pkrtz(w.z, w.w);
      }
      #pragma unroll
      for (int k=0;k<8;++k){
        float4 w = wp1[c*8+k];
        w1[c*16+2*k]   = __builtin_amdgcn_cvt_pkrtz(w.x, w.y);
        w1[c*16+2*k+1] = __builtin_amdgcn_cvt_pkrtz(w.z, w.w);
      }
    }
  }
  if (t < 256){ h32[t] = 0.f; h16[t] = (__fp16)0.f; }
  __syncthreads();

  // ---------------- 64-step scan ----------------
  const h8* hch = (const h8*)(h16 + 128*j);   // this thread's 128-f16 half
  for (int s=0;s<64;++s){
    const float gi_s = (float)gi16[s*768 + t];
    float a0 = 0.f, a1 = 0.f;          // partials for rows 2p, 2p+1
    #define DOTC(c) { const h8 hv = hch[c]; \
      a0 = __builtin_amdgcn_fdot2(w0[4*(c)  ], P0(hv), a0, false); \
      a1 = __builtin_amdgcn_fdot2(w1[4*(c)  ], P0(hv), a1, false); \
      a0 = __builtin_amdgcn_fdot2(w0[4*(c)+1], P1(hv), a0, false); \
      a1 = __builtin_amdgcn_fdot2(w1[4*(c)+1], P1(hv), a1, false); \
      a0 = __builtin_amdgcn_fdot2(w0[4*(c)+2], P2(hv), a0, false); \
      a1 = __builtin_amdgcn_fdot2(w1[4*(c)+2], P2(hv), a1, false); \
      a0 = __builtin_amdgcn_fdot2(w0[4*(c)+3], P3(hv), a0, false); \
      a1 = __builtin_amdgcn_fdot2(w1[4*(c)+3], P3(hv), a1, false); }
    DOTC(0)  DOTC(1)  DOTC(2)  DOTC(3)
    DOTC(4)  DOTC(5)  DOTC(6)  DOTC(7)
    DOTC(8)  DOTC(9)  DOTC(10) DOTC(11)
    DOTC(12) DOTC(13) DOTC(14) DOTC(15)
    #undef DOTC
    // thread j keeps partial of row 2p+j, sends the other
    const float keep = j ? a1 : a0;
    const float send = j ? a0 : a1;
    const float acc  = keep + __shfl_xor(send, 1) + bh_t;   // full dot row t
    if (t < 512) pre[t] = gi_s + acc;        // r,z pre-activations
    else       { pre[t] = gi_s; hn[t-512] = acc; }   // i_n and hn separate
    __syncthreads();
    if (t < 256){
      const float r  = sigm(pre[t]);
      const float z  = sigm(pre[256+t]);
      const float n  = tanhf(pre[512+t] + r*hn[t]);
      const float hv = (1.f - z)*n + z*h32[t];
      h32[t] = hv;
      h16[t] = (__fp16)hv;
    }
    __syncthreads();
  }

  // ---------------- attention -> fuse -> lin (h_enc == h32) ------------
  if (t < 128){
    const float4* wr = (const float4*)(aw + t*256);
    const float4* h4 = (const float4*)h32;
    float acc = ab[t];
    #pragma unroll 8
    for (int k=0;k<64;++k) acc += dot4(wr[k], h4[k]);
    f0[t] = ws[WS_IMG + t] * sigm(acc);
  }
  __syncthreads();
  if (t < 256){
    const float4* wr = (const float4*)(lw + t*128);
    const float4* h4 = (const float4*)f0;
    float acc = lb[t];
    #pragma unroll 8
    for (int k=0;k<32;++k) acc += dot4(wr[k], h4[k]);
    ws[WS_FUSED + t] = fmaxf(acc, 0.f);
  }
}

// ------------------------------------------------------------------- K3
__global__ __launch_bounds__(256) void a3c_post(
    const float* __restrict__ lwi, const float* __restrict__ lbi,
    const float* __restrict__ cx,
    const float* __restrict__ cw,  const float* __restrict__ acw,
    float* __restrict__ ws, float* __restrict__ out)
{
  const int p = blockIdx.x;            // 0..3, owns 64 LSTM units
  const int t = threadIdx.x;
  __shared__ __align__(16) float fused_lds[256];
  __shared__ float gv[256];
  __shared__ float hh[64];
  fused_lds[t] = ws[WS_FUSED + t];
  __syncthreads();
  const int g = t>>6, ul = t&63;
  const int R = (g<<8) + p*64 + ul;
  const float4* wr = (const float4*)(lwi + R*256);
  const float4* f4 = (const float4*)fused_lds;
  float acc = ws[WS_GATESH + R] + lbi[R];
  #pragma unroll 8
  for (int k=0;k<64;++k) acc += dot4(wr[k], f4[k]);
  gv[t] = acc;
  __syncthreads();
  if (t < 64){
    const int u2 = p*64 + t;
    const float iv = gv[t], fv = gv[64+t], gg = gv[128+t], ov = gv[192+t];
    const float c = sigm(fv)*cx[u2] + sigm(iv)*tanhf(gg);
    const float h = sigm(ov)*tanhf(c);
    out[5   + u2] = h;
    out[261 + u2] = c;
    hh[t] = h;
  }
  __syncthreads();
  if (t < 64){
    #pragma unroll
    for (int o=0;o<5;++o){
      const float* wrow = (o==0) ? cw : (acw + (o-1)*288);
      float pr = hh[t]*wrow[p*64 + t];
      #pragma unroll
      for (int off=32; off; off>>=1) pr += __shfl_down(pr, off, 64);
      if (t == 0) atomicAdd(out + o, pr);
    }
  }
}

extern "C" void kernel_launch(void* const* d_in, const int* in_sizes, int n_in,
                              void* d_out, int out_size, void* d_ws, size_t ws_size,
                              hipStream_t stream) {
  (void)in_sizes; (void)n_in; (void)out_size; (void)ws_size;
  const float* x    = (const float*)d_in[0];
  const int*   inst = (const int*)  d_in[1];
  const int*   tx   = (const int*)  d_in[2];
  const float* hx   = (const float*)d_in[3];
  const float* cx   = (const float*)d_in[4];
  const float* i1w  = (const float*)d_in[5];
  const float* i1b  = (const float*)d_in[6];
  const float* i2w  = (const float*)d_in[7];
  const float* i2b  = (const float*)d_in[8];
  const float* i3w  = (const float*)d_in[9];
  const float* i3b  = (const float*)d_in[10];
  const float* emb  = (const float*)d_in[11];
  const float* gwi  = (const float*)d_in[12];
  const float* gwh  = (const float*)d_in[13];
  const float* gbi  = (const float*)d_in[14];
  const float* gbh  = (const float*)d_in[15];
  const float* aw   = (const float*)d_in[16];
  const float* ab   = (const float*)d_in[17];
  const float* temb = (const float*)d_in[18];
  const float* lw   = (const float*)d_in[19];
  const float* lb   = (const float*)d_in[20];
  const float* lwi  = (const float*)d_in[21];
  const float* lwh  = (const float*)d_in[22];
  const float* lbi  = (const float*)d_in[23];
  const float* lbh  = (const float*)d_in[24];
  const float* cw   = (const float*)d_in[25];
  const float* cb   = (const float*)d_in[26];
  const float* acw  = (const float*)d_in[27];
  const float* acb  = (const float*)d_in[28];
  float* ws  = (float*)d_ws;
  float* out = (float*)d_out;

  a3c_pre <<<6, 256, 0, stream>>>(x, i1w, i1b, i2w, i2b, i3w, i3b,
                                  hx, lwh, lbh, tx, temb, cw, cb, acw, acb,
                                  ws, out);
  a3c_scan<<<1, 768, 0, stream>>>(inst, emb, gwi, gwh, gbi, gbh,
                                  aw, ab, lw, lb, ws);
  a3c_post<<<4, 256, 0, stream>>>(lwi, lbi, cx, cw, acw, ws, out);
}

// Round 6
// 146.491 us; speedup vs baseline: 1.1907x; 1.0853x over previous
//
#include <hip/hip_runtime.h>
#include <math.h>

// ---------------------------------------------------------------------------
// A3C_LSTM_GA forward, batch=1.  No cross-WG sync anywhere.
//   K1 a3c_pre  (6 blocks x 256): image MLP; gates_h = hx@lstm_wh.T+lbh;
//                                 head-bias init out[0..4]
//   K2 a3c_scan (1 block x 768): GRU scan via MFMA. Wave w owns gate-rows
//       [64w,64w+64) as 32 NAMED h8 A-fragments (128 regs, MFMA-only uses ->
//       AGPR-eligible; no private arrays -> nothing can go to scratch).
//       Per step: 1 broadcast ds_read_b128 builds B (h in col0), 32 mfma,
//       4 lanes scatter D col0 to LDS, 256 threads do gate math.
//   K3 a3c_post (4 blocks x 256): LSTM gates -> h/c -> head atomicAdd partials
// ---------------------------------------------------------------------------

typedef __fp16 h2 __attribute__((ext_vector_type(2)));
typedef __fp16 h4 __attribute__((ext_vector_type(4)));
typedef __fp16 h8 __attribute__((ext_vector_type(8)));
typedef float  f4v __attribute__((ext_vector_type(4)));

// ws layout (float offsets)
#define WS_IMG    0      // 128
#define WS_GATESH 128    // 1024
#define WS_FUSED  1152   // 256

__device__ __forceinline__ float dot4(const float4 a, const float4 b){
  return a.x*b.x + a.y*b.y + a.z*b.z + a.w*b.w;
}
__device__ __forceinline__ float sigm(float x){ return 1.f/(1.f+expf(-x)); }

#define P0(v) __builtin_shufflevector(v,v,0,1)
#define P1(v) __builtin_shufflevector(v,v,2,3)
#define P2(v) __builtin_shufflevector(v,v,4,5)
#define P3(v) __builtin_shufflevector(v,v,6,7)
#define PK(a,b) __builtin_amdgcn_cvt_pkrtz(a,b)
#define FD(w,e,acc) __builtin_amdgcn_fdot2(w,e,acc,false)

__device__ __forceinline__ h8 pack8(const float4 a, const float4 b){
  const h2 p0=PK(a.x,a.y), p1=PK(a.z,a.w), p2=PK(b.x,b.y), p3=PK(b.z,b.w);
  const h4 q0=__builtin_shufflevector(p0,p1,0,1,2,3);
  const h4 q1=__builtin_shufflevector(p2,p3,0,1,2,3);
  return __builtin_shufflevector(q0,q1,0,1,2,3,4,5,6,7);
}

// ------------------------------------------------------------------- K1
__global__ __launch_bounds__(256) void a3c_pre(
    const float* __restrict__ x,
    const float* __restrict__ i1w, const float* __restrict__ i1b,
    const float* __restrict__ i2w, const float* __restrict__ i2b,
    const float* __restrict__ i3w, const float* __restrict__ i3b,
    const float* __restrict__ hx,  const float* __restrict__ lwh,
    const float* __restrict__ lbh,
    const int*   __restrict__ tx,  const float* __restrict__ temb,
    const float* __restrict__ cw,  const float* __restrict__ cb,
    const float* __restrict__ acw, const float* __restrict__ acb,
    float* __restrict__ ws, float* __restrict__ out)
{
  const int b = blockIdx.x;
  const int t = threadIdx.x;

  if (b == 0) {
    // image MLP 400 -> 128 -> 128 -> 128
    __shared__ __align__(16) float x_lds[400];
    __shared__ __align__(16) float h1[128];
    __shared__ __align__(16) float h2s[128];
    x_lds[t] = x[t];
    if (t < 144) x_lds[256+t] = x[256+t];
    __syncthreads();
    {
      const int o = t>>1, half = t&1;
      const float4* wr = (const float4*)(i1w + o*400 + half*200);
      const float4* xr = (const float4*)(x_lds + half*200);
      float acc = 0.f;
      #pragma unroll 5
      for (int k=0;k<50;++k) acc += dot4(wr[k], xr[k]);
      acc += __shfl_down(acc, 1, 2);
      if (half == 0) h1[o] = fmaxf(acc + i1b[o], 0.f);
    }
    __syncthreads();
    if (t < 128){
      const float4* wr = (const float4*)(i2w + t*128);
      const float4* h4p = (const float4*)h1;
      float acc = i2b[t];
      #pragma unroll 8
      for (int k=0;k<32;++k) acc += dot4(wr[k], h4p[k]);
      h2s[t] = fmaxf(acc, 0.f);
    }
    __syncthreads();
    if (t < 128){
      const float4* wr = (const float4*)(i3w + t*128);
      const float4* h4p = (const float4*)h2s;
      float acc = i3b[t];
      #pragma unroll 8
      for (int k=0;k<32;++k) acc += dot4(wr[k], h4p[k]);
      ws[WS_IMG + t] = fmaxf(acc, 0.f);
    }

  } else if (b == 5) {
    // out[0..4] = bias + time-embedding partial of the heads
    if (t < 64){
      float tv = 0.f;
      if (t < 32) tv = temb[tx[0]*32 + t];
      #pragma unroll
      for (int o=0;o<5;++o){
        const float* wrow = (o==0) ? cw : (acw + (o-1)*288);
        float pr = (t < 32) ? tv*wrow[256+t] : 0.f;
        #pragma unroll
        for (int off=16; off; off>>=1) pr += __shfl_down(pr, off, 32);
        if (t == 0) out[o] = pr + ((o==0) ? cb[0] : acb[o-1]);
      }
    }

  } else {
    // blocks 1..4: gates_h = hx @ lstm_wh.T + lstm_bh
    __shared__ __align__(16) float hx_lds[256];
    hx_lds[t] = hx[t];
    __syncthreads();
    const int R = (b-1)*256 + t;
    const float4* wr = (const float4*)(lwh + R*256);
    const float4* h4p = (const float4*)hx_lds;
    float acc = lbh[R];
    #pragma unroll 8
    for (int k=0;k<64;++k) acc += dot4(wr[k], h4p[k]);
    ws[WS_GATESH + R] = acc;
  }
}

// ------------------------------------------------------------------- K2
__global__ __launch_bounds__(768) __attribute__((amdgpu_waves_per_eu(3, 3)))
void a3c_scan(
    const int*   __restrict__ inst, const float* __restrict__ emb,
    const float* __restrict__ gwi,  const float* __restrict__ gwh,
    const float* __restrict__ gbi,  const float* __restrict__ gbh,
    const float* __restrict__ aw,   const float* __restrict__ ab,
    const float* __restrict__ lw,   const float* __restrict__ lb,
    float* __restrict__ ws)
{
  const int t    = threadIdx.x;
  const int lane = t & 63;
  const int wv   = t >> 6;          // wave 0..11 -> gate-rows [64wv, 64wv+64)
  const int arow = lane & 15;       // A-row within 16-row tile
  const int kgrp = lane >> 4;       // 0..3
  const int koff = kgrp * 8;        // K offset of this lane's 8 elements
  const int rows0 = wv * 64;

  __shared__ __fp16 gi16[64*768];                   // 96 KB
  __shared__ __align__(16) __fp16 e16[2048];        // 4 KB
  __shared__ __align__(16) __fp16 h16[256];
  __shared__ float h32[256];
  __shared__ __align__(16) float acc_lds[768];
  __shared__ float bh_lds[768];
  __shared__ __align__(16) float f0[128];

  for (int i=t; i<2048; i+=768)
    e16[i] = (__fp16)emb[inst[i>>5]*32 + (i&31)];
  bh_lds[t] = gbh[t];
  const float bi_t = gbi[t];
  __syncthreads();

  // ---- gi16[s][t] = gru_wi[row t] . e_s + gbi[t]  (named regs only)
  {
    const float4* wp = (const float4*)(gwi + t*32);
    const float4 qa=wp[0], qb=wp[1], qc=wp[2], qd=wp[3],
                 qe=wp[4], qf=wp[5], qg=wp[6], qh=wp[7];
    const h2 wi0=PK(qa.x,qa.y), wi1=PK(qa.z,qa.w), wi2=PK(qb.x,qb.y), wi3=PK(qb.z,qb.w);
    const h2 wi4=PK(qc.x,qc.y), wi5=PK(qc.z,qc.w), wi6=PK(qd.x,qd.y), wi7=PK(qd.z,qd.w);
    const h2 wi8=PK(qe.x,qe.y), wi9=PK(qe.z,qe.w), wiA=PK(qf.x,qf.y), wiB=PK(qf.z,qf.w);
    const h2 wiC=PK(qg.x,qg.y), wiD=PK(qg.z,qg.w), wiE=PK(qh.x,qh.y), wiF=PK(qh.z,qh.w);
    for (int s=0;s<64;++s){
      const h8* ech = (const h8*)(e16 + s*32);
      const h8 e0=ech[0], e1=ech[1], e2=ech[2], e3=ech[3];
      float g = bi_t;
      g=FD(wi0,P0(e0),g); g=FD(wi1,P1(e0),g); g=FD(wi2,P2(e0),g); g=FD(wi3,P3(e0),g);
      g=FD(wi4,P0(e1),g); g=FD(wi5,P1(e1),g); g=FD(wi6,P2(e1),g); g=FD(wi7,P3(e1),g);
      g=FD(wi8,P0(e2),g); g=FD(wi9,P1(e2),g); g=FD(wiA,P2(e2),g); g=FD(wiB,P3(e2),g);
      g=FD(wiC,P0(e3),g); g=FD(wiD,P1(e3),g); g=FD(wiE,P2(e3),g); g=FD(wiF,P3(e3),g);
      gi16[s*768 + t] = (__fp16)g;
    }
  }

  // ---- load W_h as 32 named h8 MFMA A-fragments (tile T=0..3, ktile K=0..7)
  // lane layout per fragment: A[row = arow][k = koff + j], j=0..7
  h8 F0_0,F0_1,F0_2,F0_3,F0_4,F0_5,F0_6,F0_7;
  h8 F1_0,F1_1,F1_2,F1_3,F1_4,F1_5,F1_6,F1_7;
  h8 F2_0,F2_1,F2_2,F2_3,F2_4,F2_5,F2_6,F2_7;
  h8 F3_0,F3_1,F3_2,F3_3,F3_4,F3_5,F3_6,F3_7;
  #define LOADF(T,K) { \
    const float4* wp = (const float4*)(gwh + (rows0 + (T)*16 + arow)*256 + (K)*32 + koff); \
    F##T##_##K = pack8(wp[0], wp[1]); }
  LOADF(0,0) LOADF(0,1) LOADF(0,2) LOADF(0,3) LOADF(0,4) LOADF(0,5) LOADF(0,6) LOADF(0,7)
  LOADF(1,0) LOADF(1,1) LOADF(1,2) LOADF(1,3) LOADF(1,4) LOADF(1,5) LOADF(1,6) LOADF(1,7)
  LOADF(2,0) LOADF(2,1) LOADF(2,2) LOADF(2,3) LOADF(2,4) LOADF(2,5) LOADF(2,6) LOADF(2,7)
  LOADF(3,0) LOADF(3,1) LOADF(3,2) LOADF(3,3) LOADF(3,4) LOADF(3,5) LOADF(3,6) LOADF(3,7)
  #undef LOADF

  if (t < 256){ h32[t] = 0.f; h16[t] = (__fp16)0.f; }
  __syncthreads();

  // ---------------- 64-step scan ----------------
  const h8 hzero = {0,0,0,0,0,0,0,0};
  for (int s=0;s<64;++s){
    // B fragment: col 0 = h, cols 1..15 = 0.  B[k][col]: col=arow, k=koff+j
    const h8 hv = *(const h8*)(h16 + koff);   // 4 distinct 16B addrs, broadcast
    const h8 bf = (arow == 0) ? hv : hzero;
    f4v d0={0.f,0.f,0.f,0.f}, d1={0.f,0.f,0.f,0.f},
        d2={0.f,0.f,0.f,0.f}, d3={0.f,0.f,0.f,0.f};
    #define MMK(K) \
      d0 = __builtin_amdgcn_mfma_f32_16x16x32_f16(F0_##K, bf, d0, 0,0,0); \
      d1 = __builtin_amdgcn_mfma_f32_16x16x32_f16(F1_##K, bf, d1, 0,0,0); \
      d2 = __builtin_amdgcn_mfma_f32_16x16x32_f16(F2_##K, bf, d2, 0,0,0); \
      d3 = __builtin_amdgcn_mfma_f32_16x16x32_f16(F3_##K, bf, d3, 0,0,0);
    MMK(0) MMK(1) MMK(2) MMK(3) MMK(4) MMK(5) MMK(6) MMK(7)
    #undef MMK
    // D col0 lives in lanes arow==0: D[row=kgrp*4+reg][0]
    if (arow == 0){
      const int rb = kgrp*4;
      *(f4v*)(acc_lds + rows0      + rb) = d0;
      *(f4v*)(acc_lds + rows0 + 16 + rb) = d1;
      *(f4v*)(acc_lds + rows0 + 32 + rb) = d2;
      *(f4v*)(acc_lds + rows0 + 48 + rb) = d3;
    }
    __syncthreads();
    if (t < 256){
      const float ar = acc_lds[t]       + bh_lds[t];
      const float az = acc_lds[256 + t] + bh_lds[256 + t];
      const float an = acc_lds[512 + t] + bh_lds[512 + t];
      const float r  = sigm((float)gi16[s*768 + t]       + ar);
      const float z  = sigm((float)gi16[s*768 + 256 + t] + az);
      const float n  = tanhf((float)gi16[s*768 + 512 + t] + r*an);
      const float hvv = (1.f - z)*n + z*h32[t];
      h32[t] = hvv;
      h16[t] = (__fp16)hvv;
    }
    __syncthreads();
  }

  // ---------------- attention -> fuse -> lin (h_enc == h32) ------------
  if (t < 128){
    const float4* wr = (const float4*)(aw + t*256);
    const float4* h4p = (const float4*)h32;
    float acc = ab[t];
    #pragma unroll 8
    for (int k=0;k<64;++k) acc += dot4(wr[k], h4p[k]);
    f0[t] = ws[WS_IMG + t] * sigm(acc);
  }
  __syncthreads();
  if (t < 256){
    const float4* wr = (const float4*)(lw + t*128);
    const float4* h4p = (const float4*)f0;
    float acc = lb[t];
    #pragma unroll 8
    for (int k=0;k<32;++k) acc += dot4(wr[k], h4p[k]);
    ws[WS_FUSED + t] = fmaxf(acc, 0.f);
  }
}

// ------------------------------------------------------------------- K3
__global__ __launch_bounds__(256) void a3c_post(
    const float* __restrict__ lwi, const float* __restrict__ lbi,
    const float* __restrict__ cx,
    const float* __restrict__ cw,  const float* __restrict__ acw,
    float* __restrict__ ws, float* __restrict__ out)
{
  const int p = blockIdx.x;            // 0..3, owns 64 LSTM units
  const int t = threadIdx.x;
  __shared__ __align__(16) float fused_lds[256];
  __shared__ float gv[256];
  __shared__ float hh[64];
  fused_lds[t] = ws[WS_FUSED + t];
  __syncthreads();
  const int g = t>>6, ul = t&63;
  const int R = (g<<8) + p*64 + ul;
  const float4* wr = (const float4*)(lwi + R*256);
  const float4* f4p = (const float4*)fused_lds;
  float acc = ws[WS_GATESH + R] + lbi[R];
  #pragma unroll 8
  for (int k=0;k<64;++k) acc += dot4(wr[k], f4p[k]);
  gv[t] = acc;
  __syncthreads();
  if (t < 64){
    const int u2 = p*64 + t;
    const float iv = gv[t], fv = gv[64+t], gg = gv[128+t], ov = gv[192+t];
    const float c = sigm(fv)*cx[u2] + sigm(iv)*tanhf(gg);
    const float h = sigm(ov)*tanhf(c);
    out[5   + u2] = h;
    out[261 + u2] = c;
    hh[t] = h;
  }
  __syncthreads();
  if (t < 64){
    #pragma unroll
    for (int o=0;o<5;++o){
      const float* wrow = (o==0) ? cw : (acw + (o-1)*288);
      float pr = hh[t]*wrow[p*64 + t];
      #pragma unroll
      for (int off=32; off; off>>=1) pr += __shfl_down(pr, off, 64);
      if (t == 0) atomicAdd(out + o, pr);
    }
  }
}

extern "C" void kernel_launch(void* const* d_in, const int* in_sizes, int n_in,
                              void* d_out, int out_size, void* d_ws, size_t ws_size,
                              hipStream_t stream) {
  (void)in_sizes; (void)n_in; (void)out_size; (void)ws_size;
  const float* x    = (const float*)d_in[0];
  const int*   inst = (const int*)  d_in[1];
  const int*   tx   = (const int*)  d_in[2];
  const float* hx   = (const float*)d_in[3];
  const float* cx   = (const float*)d_in[4];
  const float* i1w  = (const float*)d_in[5];
  const float* i1b  = (const float*)d_in[6];
  const float* i2w  = (const float*)d_in[7];
  const float* i2b  = (const float*)d_in[8];
  const float* i3w  = (const float*)d_in[9];
  const float* i3b  = (const float*)d_in[10];
  const float* emb  = (const float*)d_in[11];
  const float* gwi  = (const float*)d_in[12];
  const float* gwh  = (const float*)d_in[13];
  const float* gbi  = (const float*)d_in[14];
  const float* gbh  = (const float*)d_in[15];
  const float* aw   = (const float*)d_in[16];
  const float* ab   = (const float*)d_in[17];
  const float* temb = (const float*)d_in[18];
  const float* lw   = (const float*)d_in[19];
  const float* lb   = (const float*)d_in[20];
  const float* lwi  = (const float*)d_in[21];
  const float* lwh  = (const float*)d_in[22];
  const float* lbi  = (const float*)d_in[23];
  const float* lbh  = (const float*)d_in[24];
  const float* cw   = (const float*)d_in[25];
  const float* cb   = (const float*)d_in[26];
  const float* acw  = (const float*)d_in[27];
  const float* acb  = (const float*)d_in[28];
  float* ws  = (float*)d_ws;
  float* out = (float*)d_out;

  a3c_pre <<<6, 256, 0, stream>>>(x, i1w, i1b, i2w, i2b, i3w, i3b,
                                  hx, lwh, lbh, tx, temb, cw, cb, acw, acb,
                                  ws, out);
  a3c_scan<<<1, 768, 0, stream>>>(inst, emb, gwi, gwh, gbi, gbh,
                                  aw, ab, lw, lb, ws);
  a3c_post<<<4, 256, 0, stream>>>(lwi, lbi, cx, cw, acw, ws, out);
}